// Round 10
// baseline (985.722 us; speedup 1.0000x reference)
//
#include <hip/hip_runtime.h>
#include <math.h>

// BiometricLSTM: 2-layer LSTM, B=512, T=2048, I=3, H=64, fp32 in/out. Output = final h2 (B,64).
//
// R27: R26 (best, 941.8 us) + ONE change: x-prefetch depth 1 -> 2.
// Theory: the 3 scalar x-loads issued at iter t were consumed at t+1 (~460ns
// later), but x is streamed (single-use, L3-served: FETCH 7MB < 12.6MB input)
// and L3/HBM load latency ~500-900cy ~= one iteration -> partial vmcnt stall
// at the xp computation every iteration. This stall only became visible after
// R24 replaced __syncthreads (vmcnt(0) drain at the barrier) with lds_barrier.
// Fix: two named register triples (xA*/xB*) ping-ponged by the unroll-2 parity;
// iter it consumes buf[sub] = x[it] (loaded 2 iters ago, ~1000-1800cy in
// flight) then issues the load of x[it+2] into the same named regs
// (compile-time indices, rule #20). Zero arithmetic change -> absmax must stay
// bit-identical (4.88e-4 canary).
// R26 recap (all kept): log2e-prescaled weights/biases (bare v_exp2 acts),
// L1 read-window sel4 hoists, 2-level sel4 tree; R25 split waves L0=Whh0 8 MFMA
// / L1=Whh1+Wih1 16 MFMA lag-2, pI in registers accQ[2][4] (write@sub,
// read@sub^1), no pIbuf, LDS 2560B, 0 bank conflicts; gates-before-pI order;
// unroll-2 compile-time parity; M=4 replicated rows; quad-selected update;
// HSTR=80; z-chained MFMA pairs bias-in-C; lds_barrier (lgkmcnt-only) per iter;
// f16 weights/h + f32 accum.
// Parities: h1[t]@t&1; h2[t]@t&1; accQ write@sub/read@sub^1; x buf[sub]@it&1.

typedef _Float16 half8 __attribute__((ext_vector_type(8)));
typedef float    f32x4 __attribute__((ext_vector_type(4)));

constexpr int TT = 2048;
constexpr int HSTR = 80;   // h row stride in halves (160 B)

#define LOG2E  1.44269504088896340736f
#define LOG2E2 2.88539008177792681472f

// y = x*log2e applied upstream: sigmoid(x) = 1/(1+2^-y)
__device__ __forceinline__ float sig_p(float y) {
    return __builtin_amdgcn_rcpf(1.0f + __builtin_amdgcn_exp2f(-y));
}
// y = x*2log2e applied upstream: tanh(x) = 1 - 2/(2^y + 1); saturates at +-inf
__device__ __forceinline__ float tanh_p(float y) {
    return 1.0f - 2.0f * __builtin_amdgcn_rcpf(__builtin_amdgcn_exp2f(y) + 1.0f);
}
// select component q (lane's quad) from an f32x4 accumulator — 2-level tree
__device__ __forceinline__ float sel4(f32x4 v, int q) {
    float lo = (q & 1) ? v[1] : v[0];
    float hi = (q & 1) ? v[3] : v[2];
    return (q & 2) ? hi : lo;
}

// Barrier with LDS-only drain: s_waitcnt lgkmcnt(0) + s_barrier.
// Does NOT drain vmcnt — in-flight global x-prefetch loads stay in flight
// across barriers (prerequisite for the depth-2 x prefetch).
__device__ __forceinline__ void lds_barrier() {
    __builtin_amdgcn_sched_barrier(0);
    asm volatile("s_waitcnt lgkmcnt(0)" ::: "memory");
    __builtin_amdgcn_s_barrier();
    __builtin_amdgcn_sched_barrier(0);
}

__global__ __launch_bounds__(512) void lstm2_fused(
    const float* __restrict__ x,
    const float* __restrict__ Wih0, const float* __restrict__ Whh0,
    const float* __restrict__ bih0, const float* __restrict__ bhh0,
    const float* __restrict__ Wih1, const float* __restrict__ Whh1,
    const float* __restrict__ bih1, const float* __restrict__ bhh1,
    float* __restrict__ out)
{
    __shared__ __align__(16) _Float16 h1a[2][4 * HSTR];   // [parity][seq*HSTR + elem]
    __shared__ __align__(16) _Float16 h2a[2][4 * HSTR];

    const int tid  = threadIdx.x;
    const int lane = tid & 63;
    const int wid  = tid >> 6;
    const int quad = lane >> 4;
    const int l16  = lane & 15;
    const bool isL1 = (wid >= 4);
    const int col  = (wid & 3) * 16 + l16;   // gate-elem column this lane owns per class

    // ---- zero h double-buffers ----
    for (int i = tid; i < 2 * 4 * HSTR; i += 512) {
        ((_Float16*)h1a)[i] = (_Float16)0.0f;
        ((_Float16*)h2a)[i] = (_Float16)0.0f;
    }

    // ---- weights (B-frags, f16), log2e-prescaled per gate class ----
    // class c: 0=i 1=f 2=g 3=o; scale = log2e (sigmoid) or 2*log2e (tanh g)
    half8 wA[4][2];      // L0 waves: Whh0 | L1 waves: Whh1
    half8 wB[4][2];      // L1 waves only: Wih1
    f32x4 cbias[4];      // bias splat (prescaled), MFMA C-init
    float wxa[4], wxb[4], wxc[4];            // L0 only (prescaled)
    #pragma unroll
    for (int c = 0; c < 4; ++c) {
        const int row = c * 64 + col;
        const float sc = (c == 2) ? LOG2E2 : LOG2E;
        if (!isL1) {
            #pragma unroll
            for (int f = 0; f < 2; ++f) {
                const float* p = Whh0 + (size_t)row * 64 + f * 32 + quad * 8;
                half8 h;
                #pragma unroll
                for (int u = 0; u < 8; ++u) h[u] = (_Float16)(p[u] * sc);
                wA[c][f] = h;
            }
            const float b = (bih0[row] + bhh0[row]) * sc;
            cbias[c] = f32x4{b, b, b, b};
            wxa[c] = Wih0[row*3+0] * sc;
            wxb[c] = Wih0[row*3+1] * sc;
            wxc[c] = Wih0[row*3+2] * sc;
        } else {
            #pragma unroll
            for (int f = 0; f < 2; ++f) {
                const float* p = Whh1 + (size_t)row * 64 + f * 32 + quad * 8;
                half8 h;
                #pragma unroll
                for (int u = 0; u < 8; ++u) h[u] = (_Float16)(p[u] * sc);
                wA[c][f] = h;
                const float* q = Wih1 + (size_t)row * 64 + f * 32 + quad * 8;
                half8 g;
                #pragma unroll
                for (int u = 0; u < 8; ++u) g[u] = (_Float16)(q[u] * sc);
                wB[c][f] = g;
            }
            const float b = (bih1[row] + bhh1[row]) * sc;
            cbias[c] = f32x4{b, b, b, b};
        }
    }

    // ---- x prefetch (L0 waves), DEPTH 2: named parity buffers (rule #20).
    // buf A = even steps, buf B = odd steps; iter it consumes buf[it&1]
    // (loaded at it-2) and issues the load for it+2 into the same buffer.
    const float* xq = x + (size_t)(blockIdx.x * 4 + quad) * TT * 3;
    float xA0 = 0.f, xA1 = 0.f, xA2 = 0.f;   // x[0] initially
    float xB0 = 0.f, xB1 = 0.f, xB2 = 0.f;   // x[1] initially
    if (!isL1) {
        xA0 = xq[0]; xA1 = xq[1]; xA2 = xq[2];
        xB0 = xq[3]; xB1 = xq[4]; xB2 = xq[5];
    }

    const f32x4 Z = {0.f, 0.f, 0.f, 0.f};
    float cst = 0.0f;    // cell state (layer per role, seq=quad, elem=col)

    // L1: pI double-buffer in registers; accQ[sub] written at parity sub,
    // read at sub^1. Indices are compile-time after the unroll (rule #20).
    f32x4 accQ[2][4];
    #pragma unroll
    for (int s = 0; s < 2; ++s)
        #pragma unroll
        for (int c = 0; c < 4; ++c) accQ[s][c] = Z;

    __syncthreads();   // init barrier: full drain fine here (once)

    // iter it = 0 .. TT+1 in unrolled pairs (cur/prev compile-time).
    // L0: step it (it<TT).  L1: gates for step it-2 (it>=2) + pI(it-1) (1<=it<=TT).
    // ONE lds_barrier per iteration.
    for (int bt = 0; bt <= TT + 1; bt += 2) {
        #pragma unroll
        for (int sub = 0; sub < 2; ++sub) {
            const int it   = bt + sub;
            const int cur  = sub;        // bt even => it&1 == sub
            const int prev = sub ^ 1;

            if (!isL1) {
                if (it < TT) {
                    // A-frags: h1[it-1] (parity prev), replicated rows
                    const _Float16* hb = h1a[prev] + (l16 & 3) * HSTR + quad * 8;
                    half8 a0 = *(const half8*)hb;
                    half8 a1 = *(const half8*)(hb + 32);

                    // x[it] from the parity buffer (loaded 2 iters ago, vmcnt
                    // long satisfied). x-projection fills the ds_read window.
                    float x0, x1, x2;
                    if (sub == 0) { x0 = xA0; x1 = xA1; x2 = xA2; }
                    else          { x0 = xB0; x1 = xB1; x2 = xB2; }
                    float xp0 = fmaf(wxa[0], x0, fmaf(wxb[0], x1, wxc[0] * x2));
                    float xp1 = fmaf(wxa[1], x0, fmaf(wxb[1], x1, wxc[1] * x2));
                    float xp2 = fmaf(wxa[2], x0, fmaf(wxb[2], x1, wxc[2] * x2));
                    float xp3 = fmaf(wxa[3], x0, fmaf(wxb[3], x1, wxc[3] * x2));
                    // issue load of x[it+2] into the SAME parity buffer; stays
                    // in flight across the next 2 lds_barriers (no vmcnt drain).
                    const int nt = (it + 2 < TT) ? it + 2 : TT - 1;
                    const float* np = xq + nt * 3;
                    if (sub == 0) { xA0 = np[0]; xA1 = np[1]; xA2 = np[2]; }
                    else          { xB0 = np[0]; xB1 = np[1]; xB2 = np[2]; }

                    // L0 gates: Whh0 . h1[it-1] + bias (in C) — the pole.
                    f32x4 acc[4];
                    #pragma unroll
                    for (int c = 0; c < 4; ++c) {
                        f32x4 z = cbias[c];
                        z = __builtin_amdgcn_mfma_f32_16x16x32_f16(a0, wA[c][0], z, 0, 0, 0);
                        z = __builtin_amdgcn_mfma_f32_16x16x32_f16(a1, wA[c][1], z, 0, 0, 0);
                        acc[c] = z;
                    }
                    float pi = sel4(acc[0], quad) + xp0;
                    float pf = sel4(acc[1], quad) + xp1;
                    float pg = sel4(acc[2], quad) + xp2;
                    float po = sel4(acc[3], quad) + xp3;
                    float iv = sig_p(pi),  fv = sig_p(pf);
                    float gv = tanh_p(pg), ov = sig_p(po);
                    cst = fmaf(fv, cst, iv * gv);
                    float th = tanh_p(cst * LOG2E2);
                    h1a[cur][quad * HSTR + col] = (_Float16)(ov * th); // h1[it]
                }
            } else {
                const bool doG = (it >= 2);             // gates for step it-2
                const bool doQ = (it >= 1 && it <= TT); // pI(it-1) for next iter

                // ds_reads first (both frag sets issue together)
                half8 a2, a3, b0, b1;
                if (doG) {
                    const _Float16* hb2 = h2a[prev] + (l16 & 3) * HSTR + quad * 8;
                    a2 = *(const half8*)hb2;
                    a3 = *(const half8*)(hb2 + 32);
                }
                if (doQ) {
                    const _Float16* hb1 = h1a[prev] + (l16 & 3) * HSTR + quad * 8;
                    b0 = *(const half8*)hb1;
                    b1 = *(const half8*)(hb1 + 32);
                }

                // read-window fill: pI(it-2) quad-selects (off the tail chain)
                float qp0, qp1, qp2, qp3;
                if (doG) {
                    qp0 = sel4(accQ[prev][0], quad);
                    qp1 = sel4(accQ[prev][1], quad);
                    qp2 = sel4(accQ[prev][2], quad);
                    qp3 = sel4(accQ[prev][3], quad);
                }

                // CRITICAL: gate MFMAs issue first (in-order MFMA pipe).
                f32x4 acc[4];
                if (doG) {
                    #pragma unroll
                    for (int c = 0; c < 4; ++c) {
                        f32x4 z = cbias[c];
                        z = __builtin_amdgcn_mfma_f32_16x16x32_f16(a2, wA[c][0], z, 0, 0, 0);
                        z = __builtin_amdgcn_mfma_f32_16x16x32_f16(a3, wA[c][1], z, 0, 0, 0);
                        acc[c] = z;
                    }
                }
                // pI(it-1) = Wih1 . h1[it-1] -> accQ[sub] (registers, consumed
                // NEXT iteration). Off-critical; issues behind gates, completes
                // under the VALU activation tail.
                if (doQ) {
                    #pragma unroll
                    for (int c = 0; c < 4; ++c) {
                        f32x4 z = Z;
                        z = __builtin_amdgcn_mfma_f32_16x16x32_f16(b0, wB[c][0], z, 0, 0, 0);
                        z = __builtin_amdgcn_mfma_f32_16x16x32_f16(b1, wB[c][1], z, 0, 0, 0);
                        accQ[sub][c] = z;
                    }
                }

                if (doG) {
                    // gates = Whh1.h2[it-3] + bias + pI(it-2) (hoisted qp)
                    float pi = sel4(acc[0], quad) + qp0;
                    float pf = sel4(acc[1], quad) + qp1;
                    float pg = sel4(acc[2], quad) + qp2;
                    float po = sel4(acc[3], quad) + qp3;
                    float iv = sig_p(pi),  fv = sig_p(pf);
                    float gv = tanh_p(pg), ov = sig_p(po);
                    cst = fmaf(fv, cst, iv * gv);
                    float hv = ov * tanh_p(cst * LOG2E2);
                    h2a[cur][quad * HSTR + col] = (_Float16)hv;            // h2[it-2]
                    if (it == TT + 1)
                        out[(size_t)(blockIdx.x * 4 + quad) * 64 + col] = hv;
                }
            }
            lds_barrier();   // LDS-only drain; x prefetch stays in flight
        }
    }
}

extern "C" void kernel_launch(void* const* d_in, const int* in_sizes, int n_in,
                              void* d_out, int out_size, void* d_ws, size_t ws_size,
                              hipStream_t stream) {
    const float* x    = (const float*)d_in[0];
    const float* Wih0 = (const float*)d_in[1];
    const float* Whh0 = (const float*)d_in[2];
    const float* bih0 = (const float*)d_in[3];
    const float* bhh0 = (const float*)d_in[4];
    const float* Wih1 = (const float*)d_in[5];
    const float* Whh1 = (const float*)d_in[6];
    const float* bih1 = (const float*)d_in[7];
    const float* bhh1 = (const float*)d_in[8];
    float* out = (float*)d_out;

    // 512 sequences / 4 per block = 128 blocks; 512 threads (8 waves, 2/SIMD).
    lstm2_fused<<<128, 512, 0, stream>>>(x, Wih0, Whh0, bih0, bhh0,
                                         Wih1, Whh1, bih1, bhh1, out);
}

// Round 11
// 978.188 us; speedup vs baseline: 1.0077x; 1.0077x over previous
//
#include <hip/hip_runtime.h>
#include <math.h>

// BiometricLSTM: 2-layer LSTM, B=512, T=2048, I=3, H=64, fp32 in/out. Output = final h2 (B,64).
//
// R28: R26 (best, 941.8 us) + MFMA rebalance 8/16 -> 12/12. R27 (x depth-2) is
// REVERTED: it regressed +4.7% and refuted the x-latency theory (loads arrive
// in time; the named-buffer ping-pong added v_mov register motion).
// Theory: both roles barrier-sync every iter, so T_iter = max(L0, L1). L1 was
// the pole: 16 MFMA issues + 4 ds_reads vs L0's 8 + 2 (~40-80cy skew, idled by
// L0 at 2050 barriers). Split pI=Wih1.h1 by gate class:
//   L0: gates (8 MFMA) + pI classes 0,1 (4 MFMA, REUSING its a0/a1 frags —
//       no extra ds_reads) -> pIbuf[2][2][64] float4 (4KB; write@prev).
//   L1: gates (8 MFMA) + pI classes 2,3 (4 MFMA) -> accQ regs (read@sub^1);
//       classes 0,1 partials read from pIbuf[cur] in the ds_read window.
// pIbuf parity identical to R20's verified scheme (write@prev / read@cur
// disjoint). Bank behavior: writes 16 lanes x float4 = 2-way (free, m136);
// reads 64 lanes b32 = 2-way. Arithmetic bit-identical (same z-chain, same f16
// inputs, f32 transported exactly) -> absmax canary 4.88e-4 must hold.
// Side value: if this REGRESSES, R25's win was the LDS-removal, not the
// rebalance — either outcome is informative.
// R26 recap (all kept): log2e-prescaled weights/biases (bare v_exp2 acts),
// L1 read-window sel4 hoists, 2-level sel4 tree, x prefetch depth-1;
// R25: no pIbuf for classes 2,3 (regs), LDS small, 0 conflicts; gates-before-pI
// issue order; unroll-2 compile-time parity; M=4 replicated rows; quad-selected
// update; HSTR=80; z-chained MFMA pairs bias-in-C; lds_barrier (lgkmcnt-only)
// per iter; f16 weights/h + f32 accum.
// Parities: h1[t]@t&1; h2[t]@t&1; accQ write@sub/read@sub^1; pIbuf write@prev/read@cur.

typedef _Float16 half8 __attribute__((ext_vector_type(8)));
typedef float    f32x4 __attribute__((ext_vector_type(4)));

constexpr int TT = 2048;
constexpr int HSTR = 80;   // h row stride in halves (160 B)

#define LOG2E  1.44269504088896340736f
#define LOG2E2 2.88539008177792681472f

// y = x*log2e applied upstream: sigmoid(x) = 1/(1+2^-y)
__device__ __forceinline__ float sig_p(float y) {
    return __builtin_amdgcn_rcpf(1.0f + __builtin_amdgcn_exp2f(-y));
}
// y = x*2log2e applied upstream: tanh(x) = 1 - 2/(2^y + 1); saturates at +-inf
__device__ __forceinline__ float tanh_p(float y) {
    return 1.0f - 2.0f * __builtin_amdgcn_rcpf(__builtin_amdgcn_exp2f(y) + 1.0f);
}
// select component q (lane's quad) from an f32x4 accumulator — 2-level tree
__device__ __forceinline__ float sel4(f32x4 v, int q) {
    float lo = (q & 1) ? v[1] : v[0];
    float hi = (q & 1) ? v[3] : v[2];
    return (q & 2) ? hi : lo;
}

// Barrier with LDS-only drain: s_waitcnt lgkmcnt(0) + s_barrier.
// Does NOT drain vmcnt — in-flight global x-prefetch loads stay in flight.
__device__ __forceinline__ void lds_barrier() {
    __builtin_amdgcn_sched_barrier(0);
    asm volatile("s_waitcnt lgkmcnt(0)" ::: "memory");
    __builtin_amdgcn_s_barrier();
    __builtin_amdgcn_sched_barrier(0);
}

__global__ __launch_bounds__(512) void lstm2_fused(
    const float* __restrict__ x,
    const float* __restrict__ Wih0, const float* __restrict__ Whh0,
    const float* __restrict__ bih0, const float* __restrict__ bhh0,
    const float* __restrict__ Wih1, const float* __restrict__ Whh1,
    const float* __restrict__ bih1, const float* __restrict__ bhh1,
    float* __restrict__ out)
{
    __shared__ __align__(16) _Float16 h1a[2][4 * HSTR];   // [parity][seq*HSTR + elem]
    __shared__ __align__(16) _Float16 h2a[2][4 * HSTR];
    __shared__ __align__(16) float4   pIbuf[2][2][64];    // [stepParity][class 0,1][col]

    const int tid  = threadIdx.x;
    const int lane = tid & 63;
    const int wid  = tid >> 6;
    const int quad = lane >> 4;
    const int l16  = lane & 15;
    const bool isL1 = (wid >= 4);
    const int col  = (wid & 3) * 16 + l16;   // gate-elem column this lane owns per class

    // ---- zero h double-buffers ----
    for (int i = tid; i < 2 * 4 * HSTR; i += 512) {
        ((_Float16*)h1a)[i] = (_Float16)0.0f;
        ((_Float16*)h2a)[i] = (_Float16)0.0f;
    }

    // ---- weights (B-frags, f16), log2e-prescaled per gate class ----
    // class c: 0=i 1=f 2=g 3=o; scale = log2e (sigmoid) or 2*log2e (tanh g)
    half8 wA[4][2];      // L0 waves: Whh0 | L1 waves: Whh1
    half8 wP[2][2];      // L0: Wih1 classes 0,1 | L1: Wih1 classes 2,3
    f32x4 cbias[4];      // bias splat (prescaled), MFMA C-init
    float wxa[4], wxb[4], wxc[4];            // L0 only (prescaled)
    #pragma unroll
    for (int c = 0; c < 4; ++c) {
        const int row = c * 64 + col;
        const float sc = (c == 2) ? LOG2E2 : LOG2E;
        if (!isL1) {
            #pragma unroll
            for (int f = 0; f < 2; ++f) {
                const float* p = Whh0 + (size_t)row * 64 + f * 32 + quad * 8;
                half8 h;
                #pragma unroll
                for (int u = 0; u < 8; ++u) h[u] = (_Float16)(p[u] * sc);
                wA[c][f] = h;
            }
            const float b = (bih0[row] + bhh0[row]) * sc;
            cbias[c] = f32x4{b, b, b, b};
            wxa[c] = Wih0[row*3+0] * sc;
            wxb[c] = Wih0[row*3+1] * sc;
            wxc[c] = Wih0[row*3+2] * sc;
            if (c < 2) {   // pI classes 0,1 live on L0
                #pragma unroll
                for (int f = 0; f < 2; ++f) {
                    const float* q = Wih1 + (size_t)row * 64 + f * 32 + quad * 8;
                    half8 g;
                    #pragma unroll
                    for (int u = 0; u < 8; ++u) g[u] = (_Float16)(q[u] * sc);
                    wP[c][f] = g;
                }
            }
        } else {
            #pragma unroll
            for (int f = 0; f < 2; ++f) {
                const float* p = Whh1 + (size_t)row * 64 + f * 32 + quad * 8;
                half8 h;
                #pragma unroll
                for (int u = 0; u < 8; ++u) h[u] = (_Float16)(p[u] * sc);
                wA[c][f] = h;
            }
            const float b = (bih1[row] + bhh1[row]) * sc;
            cbias[c] = f32x4{b, b, b, b};
            if (c >= 2) {   // pI classes 2,3 live on L1
                #pragma unroll
                for (int f = 0; f < 2; ++f) {
                    const float* q = Wih1 + (size_t)row * 64 + f * 32 + quad * 8;
                    half8 g;
                    #pragma unroll
                    for (int u = 0; u < 8; ++u) g[u] = (_Float16)(q[u] * sc);
                    wP[c - 2][f] = g;
                }
            }
        }
    }

    // ---- x prefetch (L0 waves), depth 1 (R26 form): this lane's seq = quad ----
    const float* xq = x + (size_t)(blockIdx.x * 4 + quad) * TT * 3;
    float xn0 = 0.f, xn1 = 0.f, xn2 = 0.f;
    if (!isL1) { xn0 = xq[0]; xn1 = xq[1]; xn2 = xq[2]; }

    const f32x4 Z = {0.f, 0.f, 0.f, 0.f};
    float cst = 0.0f;    // cell state (layer per role, seq=quad, elem=col)

    // L1: pI classes 2,3 double-buffer in registers (write@sub, read@sub^1)
    f32x4 accQ[2][2];
    #pragma unroll
    for (int s = 0; s < 2; ++s) {
        accQ[s][0] = Z; accQ[s][1] = Z;
    }

    __syncthreads();   // init barrier: full drain fine here (once)

    // iter it = 0 .. TT+1 in unrolled pairs (cur/prev compile-time).
    // L0: gates step it (it<TT) + pI(it-1) classes 0,1 (1<=it<=TT).
    // L1: gates step it-2 (it>=2) + pI(it-1) classes 2,3 (1<=it<=TT).
    // ONE lds_barrier per iteration.
    for (int bt = 0; bt <= TT + 1; bt += 2) {
        #pragma unroll
        for (int sub = 0; sub < 2; ++sub) {
            const int it   = bt + sub;
            const int cur  = sub;        // bt even => it&1 == sub
            const int prev = sub ^ 1;

            if (!isL1) {
                if (it <= TT) {
                    // A-frags: h1[it-1] (parity prev), replicated rows
                    const _Float16* hb = h1a[prev] + (l16 & 3) * HSTR + quad * 8;
                    half8 a0 = *(const half8*)hb;
                    half8 a1 = *(const half8*)(hb + 32);

                    const bool doGate = (it < TT);
                    const bool doP    = (it >= 1);   // pI(it-1), it<=TT implied

                    f32x4 acc[4];
                    float xp0, xp1, xp2, xp3;
                    if (doGate) {
                        // x-projection (prescaled): fills the ds_read window.
                        const float x0 = xn0, x1 = xn1, x2 = xn2;
                        xp0 = fmaf(wxa[0], x0, fmaf(wxb[0], x1, wxc[0] * x2));
                        xp1 = fmaf(wxa[1], x0, fmaf(wxb[1], x1, wxc[1] * x2));
                        xp2 = fmaf(wxa[2], x0, fmaf(wxb[2], x1, wxc[2] * x2));
                        xp3 = fmaf(wxa[3], x0, fmaf(wxb[3], x1, wxc[3] * x2));
                        const int nt = (it + 1 < TT) ? it + 1 : TT - 1;
                        const float* np = xq + nt * 3;
                        xn0 = np[0]; xn1 = np[1]; xn2 = np[2];

                        // CRITICAL: gate MFMAs issue first (in-order MFMA pipe).
                        #pragma unroll
                        for (int c = 0; c < 4; ++c) {
                            f32x4 z = cbias[c];
                            z = __builtin_amdgcn_mfma_f32_16x16x32_f16(a0, wA[c][0], z, 0, 0, 0);
                            z = __builtin_amdgcn_mfma_f32_16x16x32_f16(a1, wA[c][1], z, 0, 0, 0);
                            acc[c] = z;
                        }
                    }

                    // pI(it-1) classes 0,1 (reuses a0/a1; off-critical — consumed
                    // by L1 next iteration via pIbuf). Issues behind gates.
                    f32x4 accP0, accP1;
                    if (doP) {
                        f32x4 z0 = Z, z1 = Z;
                        z0 = __builtin_amdgcn_mfma_f32_16x16x32_f16(a0, wP[0][0], z0, 0, 0, 0);
                        z0 = __builtin_amdgcn_mfma_f32_16x16x32_f16(a1, wP[0][1], z0, 0, 0, 0);
                        z1 = __builtin_amdgcn_mfma_f32_16x16x32_f16(a0, wP[1][0], z1, 0, 0, 0);
                        z1 = __builtin_amdgcn_mfma_f32_16x16x32_f16(a1, wP[1][1], z1, 0, 0, 0);
                        accP0 = z0; accP1 = z1;
                    }

                    if (doGate) {
                        float pi = sel4(acc[0], quad) + xp0;
                        float pf = sel4(acc[1], quad) + xp1;
                        float pg = sel4(acc[2], quad) + xp2;
                        float po = sel4(acc[3], quad) + xp3;
                        float iv = sig_p(pi),  fv = sig_p(pf);
                        float gv = tanh_p(pg), ov = sig_p(po);
                        cst = fmaf(fv, cst, iv * gv);
                        float th = tanh_p(cst * LOG2E2);
                        h1a[cur][quad * HSTR + col] = (_Float16)(ov * th); // h1[it]
                    }

                    if (doP && quad == 0) {
                        pIbuf[prev][0][col] = make_float4(accP0[0], accP0[1],
                                                          accP0[2], accP0[3]);
                        pIbuf[prev][1][col] = make_float4(accP1[0], accP1[1],
                                                          accP1[2], accP1[3]);
                    }
                }
            } else {
                const bool doG = (it >= 2);             // gates for step it-2
                const bool doQ = (it >= 1 && it <= TT); // pI(it-1) classes 2,3

                // ds_reads first (both frag sets issue together)
                half8 a2, a3, b0, b1;
                if (doG) {
                    const _Float16* hb2 = h2a[prev] + (l16 & 3) * HSTR + quad * 8;
                    a2 = *(const half8*)hb2;
                    a3 = *(const half8*)(hb2 + 32);
                }
                if (doQ) {
                    const _Float16* hb1 = h1a[prev] + (l16 & 3) * HSTR + quad * 8;
                    b0 = *(const half8*)hb1;
                    b1 = *(const half8*)(hb1 + 32);
                }

                // read-window fill: pI(it-2) partials — classes 0,1 from pIbuf
                // (written by L0 last iter, 2-way banks), 2,3 from accQ regs.
                float qp0, qp1, qp2, qp3;
                if (doG) {
                    const float* pb = (const float*)&pIbuf[cur][0][col] + quad;
                    qp0 = pb[0];
                    qp1 = pb[256];
                    qp2 = sel4(accQ[prev][0], quad);
                    qp3 = sel4(accQ[prev][1], quad);
                }

                // CRITICAL: gate MFMAs issue first (in-order MFMA pipe).
                f32x4 acc[4];
                if (doG) {
                    #pragma unroll
                    for (int c = 0; c < 4; ++c) {
                        f32x4 z = cbias[c];
                        z = __builtin_amdgcn_mfma_f32_16x16x32_f16(a2, wA[c][0], z, 0, 0, 0);
                        z = __builtin_amdgcn_mfma_f32_16x16x32_f16(a3, wA[c][1], z, 0, 0, 0);
                        acc[c] = z;
                    }
                }
                // pI(it-1) classes 2,3 -> accQ[sub] (consumed NEXT iteration).
                if (doQ) {
                    f32x4 z2 = Z, z3 = Z;
                    z2 = __builtin_amdgcn_mfma_f32_16x16x32_f16(b0, wP[0][0], z2, 0, 0, 0);
                    z2 = __builtin_amdgcn_mfma_f32_16x16x32_f16(b1, wP[0][1], z2, 0, 0, 0);
                    z3 = __builtin_amdgcn_mfma_f32_16x16x32_f16(b0, wP[1][0], z3, 0, 0, 0);
                    z3 = __builtin_amdgcn_mfma_f32_16x16x32_f16(b1, wP[1][1], z3, 0, 0, 0);
                    accQ[sub][0] = z2;
                    accQ[sub][1] = z3;
                }

                if (doG) {
                    // gates = Whh1.h2[it-3] + bias + pI(it-2)
                    float pi = sel4(acc[0], quad) + qp0;
                    float pf = sel4(acc[1], quad) + qp1;
                    float pg = sel4(acc[2], quad) + qp2;
                    float po = sel4(acc[3], quad) + qp3;
                    float iv = sig_p(pi),  fv = sig_p(pf);
                    float gv = tanh_p(pg), ov = sig_p(po);
                    cst = fmaf(fv, cst, iv * gv);
                    float hv = ov * tanh_p(cst * LOG2E2);
                    h2a[cur][quad * HSTR + col] = (_Float16)hv;            // h2[it-2]
                    if (it == TT + 1)
                        out[(size_t)(blockIdx.x * 4 + quad) * 64 + col] = hv;
                }
            }
            lds_barrier();   // LDS-only drain; x prefetch stays in flight
        }
    }
}

extern "C" void kernel_launch(void* const* d_in, const int* in_sizes, int n_in,
                              void* d_out, int out_size, void* d_ws, size_t ws_size,
                              hipStream_t stream) {
    const float* x    = (const float*)d_in[0];
    const float* Wih0 = (const float*)d_in[1];
    const float* Whh0 = (const float*)d_in[2];
    const float* bih0 = (const float*)d_in[3];
    const float* bhh0 = (const float*)d_in[4];
    const float* Wih1 = (const float*)d_in[5];
    const float* Whh1 = (const float*)d_in[6];
    const float* bih1 = (const float*)d_in[7];
    const float* bhh1 = (const float*)d_in[8];
    float* out = (float*)d_out;

    // 512 sequences / 4 per block = 128 blocks; 512 threads (8 waves, 2/SIMD).
    lstm2_fused<<<128, 512, 0, stream>>>(x, Wih0, Whh0, bih0, bhh0,
                                         Wih1, Whh1, bih1, bhh1, out);
}

// Round 12
// 940.489 us; speedup vs baseline: 1.0481x; 1.0401x over previous
//
#include <hip/hip_runtime.h>
#include <math.h>

// BiometricLSTM: 2-layer LSTM, B=512, T=2048, I=3, H=64, fp32 in/out. Output = final h2 (B,64).
//
// R29: R26 (best, 941.8 us) + ONE variable: static s_setprio(1) on L0 waves.
// R28 post-mortem: 12/12 rebalance REGRESSED +3.9% (bank conflicts 0 -> 4.19M:
// the pIbuf LDS round-trip was the cost, not the skew) -> R25's win was the
// LDS-removal; barrier skew between roles is hidden by SIMD co-scheduling.
// R28 reverted entirely.
// Theory here: the 2 waves/SIMD contend for issue slots at phase starts (both
// ds_read after the barrier, both run MFMAs). The h1 recurrence runs through
// L0's ENTIRE chain (read->MFMA->tail->write) and feeds both roles next iter;
// L1's pI has a full iteration of slack. Priority should protect L0 at
// contention points (T5: setprio pays with role diversity; R23's test was
// confounded — this is the clean isolation). Sign of the delta identifies the
// pole wave either way.
// R26 recap (all kept): log2e-prescaled weights/biases (bare v_exp2 acts),
// L1 read-window sel4 hoists, 2-level sel4 tree; split waves L0=Whh0 8 MFMA /
// L1=Whh1+Wih1 16 MFMA lag-2; pI in registers accQ[2][4] (write@sub,
// read@sub^1), no pIbuf, LDS 2560B, 0 bank conflicts; gates-before-pI issue
// order; unroll-2 compile-time parity; M=4 replicated rows; quad-selected
// update; HSTR=80; z-chained MFMA pairs bias-in-C; x prefetch depth-1;
// lds_barrier (lgkmcnt-only drain) once per iter; f16 weights/h + f32 accum.
// Parities: h1[t]@t&1; h2[t]@t&1; accQ write@sub / read@sub^1.

typedef _Float16 half8 __attribute__((ext_vector_type(8)));
typedef float    f32x4 __attribute__((ext_vector_type(4)));

constexpr int TT = 2048;
constexpr int HSTR = 80;   // h row stride in halves (160 B)

#define LOG2E  1.44269504088896340736f
#define LOG2E2 2.88539008177792681472f

// y = x*log2e applied upstream: sigmoid(x) = 1/(1+2^-y)
__device__ __forceinline__ float sig_p(float y) {
    return __builtin_amdgcn_rcpf(1.0f + __builtin_amdgcn_exp2f(-y));
}
// y = x*2log2e applied upstream: tanh(x) = 1 - 2/(2^y + 1); saturates at +-inf
__device__ __forceinline__ float tanh_p(float y) {
    return 1.0f - 2.0f * __builtin_amdgcn_rcpf(__builtin_amdgcn_exp2f(y) + 1.0f);
}
// select component q (lane's quad) from an f32x4 accumulator — 2-level tree
__device__ __forceinline__ float sel4(f32x4 v, int q) {
    float lo = (q & 1) ? v[1] : v[0];
    float hi = (q & 1) ? v[3] : v[2];
    return (q & 2) ? hi : lo;
}

// Barrier with LDS-only drain: s_waitcnt lgkmcnt(0) + s_barrier.
// Does NOT drain vmcnt — in-flight global x-prefetch loads stay in flight.
__device__ __forceinline__ void lds_barrier() {
    __builtin_amdgcn_sched_barrier(0);
    asm volatile("s_waitcnt lgkmcnt(0)" ::: "memory");
    __builtin_amdgcn_s_barrier();
    __builtin_amdgcn_sched_barrier(0);
}

__global__ __launch_bounds__(512) void lstm2_fused(
    const float* __restrict__ x,
    const float* __restrict__ Wih0, const float* __restrict__ Whh0,
    const float* __restrict__ bih0, const float* __restrict__ bhh0,
    const float* __restrict__ Wih1, const float* __restrict__ Whh1,
    const float* __restrict__ bih1, const float* __restrict__ bhh1,
    float* __restrict__ out)
{
    __shared__ __align__(16) _Float16 h1a[2][4 * HSTR];   // [parity][seq*HSTR + elem]
    __shared__ __align__(16) _Float16 h2a[2][4 * HSTR];

    const int tid  = threadIdx.x;
    const int lane = tid & 63;
    const int wid  = tid >> 6;
    const int quad = lane >> 4;
    const int l16  = lane & 15;
    const bool isL1 = (wid >= 4);
    const int col  = (wid & 3) * 16 + l16;   // gate-elem column this lane owns per class

    // ---- zero h double-buffers ----
    for (int i = tid; i < 2 * 4 * HSTR; i += 512) {
        ((_Float16*)h1a)[i] = (_Float16)0.0f;
        ((_Float16*)h2a)[i] = (_Float16)0.0f;
    }

    // ---- weights (B-frags, f16), log2e-prescaled per gate class ----
    // class c: 0=i 1=f 2=g 3=o; scale = log2e (sigmoid) or 2*log2e (tanh g)
    half8 wA[4][2];      // L0 waves: Whh0 | L1 waves: Whh1
    half8 wB[4][2];      // L1 waves only: Wih1
    f32x4 cbias[4];      // bias splat (prescaled), MFMA C-init
    float wxa[4], wxb[4], wxc[4];            // L0 only (prescaled)
    #pragma unroll
    for (int c = 0; c < 4; ++c) {
        const int row = c * 64 + col;
        const float sc = (c == 2) ? LOG2E2 : LOG2E;
        if (!isL1) {
            #pragma unroll
            for (int f = 0; f < 2; ++f) {
                const float* p = Whh0 + (size_t)row * 64 + f * 32 + quad * 8;
                half8 h;
                #pragma unroll
                for (int u = 0; u < 8; ++u) h[u] = (_Float16)(p[u] * sc);
                wA[c][f] = h;
            }
            const float b = (bih0[row] + bhh0[row]) * sc;
            cbias[c] = f32x4{b, b, b, b};
            wxa[c] = Wih0[row*3+0] * sc;
            wxb[c] = Wih0[row*3+1] * sc;
            wxc[c] = Wih0[row*3+2] * sc;
        } else {
            #pragma unroll
            for (int f = 0; f < 2; ++f) {
                const float* p = Whh1 + (size_t)row * 64 + f * 32 + quad * 8;
                half8 h;
                #pragma unroll
                for (int u = 0; u < 8; ++u) h[u] = (_Float16)(p[u] * sc);
                wA[c][f] = h;
                const float* q = Wih1 + (size_t)row * 64 + f * 32 + quad * 8;
                half8 g;
                #pragma unroll
                for (int u = 0; u < 8; ++u) g[u] = (_Float16)(q[u] * sc);
                wB[c][f] = g;
            }
            const float b = (bih1[row] + bhh1[row]) * sc;
            cbias[c] = f32x4{b, b, b, b};
        }
    }

    // ---- x prefetch (L0 waves), depth 1: this lane's seq = quad ----
    const float* xq = x + (size_t)(blockIdx.x * 4 + quad) * TT * 3;
    float xn0 = 0.f, xn1 = 0.f, xn2 = 0.f;
    if (!isL1) { xn0 = xq[0]; xn1 = xq[1]; xn2 = xq[2]; }

    const f32x4 Z = {0.f, 0.f, 0.f, 0.f};
    float cst = 0.0f;    // cell state (layer per role, seq=quad, elem=col)

    // L1: pI double-buffer in registers; accQ[sub] written at parity sub,
    // read at sub^1. Indices are compile-time after the unroll (rule #20).
    f32x4 accQ[2][4];
    #pragma unroll
    for (int s = 0; s < 2; ++s)
        #pragma unroll
        for (int c = 0; c < 4; ++c) accQ[s][c] = Z;

    // R29: protect the h1-recurrence wave at issue-contention points.
    if (!isL1) __builtin_amdgcn_s_setprio(1);

    __syncthreads();   // init barrier: full drain fine here (once)

    // iter it = 0 .. TT+1 in unrolled pairs (cur/prev compile-time).
    // L0: step it (it<TT).  L1: gates for step it-2 (it>=2) + pI(it-1) (1<=it<=TT).
    // ONE lds_barrier per iteration.
    for (int bt = 0; bt <= TT + 1; bt += 2) {
        #pragma unroll
        for (int sub = 0; sub < 2; ++sub) {
            const int it   = bt + sub;
            const int cur  = sub;        // bt even => it&1 == sub
            const int prev = sub ^ 1;

            if (!isL1) {
                if (it < TT) {
                    // A-frags: h1[it-1] (parity prev), replicated rows
                    const _Float16* hb = h1a[prev] + (l16 & 3) * HSTR + quad * 8;
                    half8 a0 = *(const half8*)hb;
                    half8 a1 = *(const half8*)(hb + 32);

                    // x-projection (prescaled): fills the ds_read window.
                    const float x0 = xn0, x1 = xn1, x2 = xn2;
                    float xp0 = fmaf(wxa[0], x0, fmaf(wxb[0], x1, wxc[0] * x2));
                    float xp1 = fmaf(wxa[1], x0, fmaf(wxb[1], x1, wxc[1] * x2));
                    float xp2 = fmaf(wxa[2], x0, fmaf(wxb[2], x1, wxc[2] * x2));
                    float xp3 = fmaf(wxa[3], x0, fmaf(wxb[3], x1, wxc[3] * x2));
                    const int nt = (it + 1 < TT) ? it + 1 : TT - 1;
                    const float* np = xq + nt * 3;
                    xn0 = np[0]; xn1 = np[1]; xn2 = np[2];

                    // L0 gates: Whh0 . h1[it-1] + bias (in C) — the pole.
                    f32x4 acc[4];
                    #pragma unroll
                    for (int c = 0; c < 4; ++c) {
                        f32x4 z = cbias[c];
                        z = __builtin_amdgcn_mfma_f32_16x16x32_f16(a0, wA[c][0], z, 0, 0, 0);
                        z = __builtin_amdgcn_mfma_f32_16x16x32_f16(a1, wA[c][1], z, 0, 0, 0);
                        acc[c] = z;
                    }
                    float pi = sel4(acc[0], quad) + xp0;
                    float pf = sel4(acc[1], quad) + xp1;
                    float pg = sel4(acc[2], quad) + xp2;
                    float po = sel4(acc[3], quad) + xp3;
                    float iv = sig_p(pi),  fv = sig_p(pf);
                    float gv = tanh_p(pg), ov = sig_p(po);
                    cst = fmaf(fv, cst, iv * gv);
                    float th = tanh_p(cst * LOG2E2);
                    h1a[cur][quad * HSTR + col] = (_Float16)(ov * th); // h1[it]
                }
            } else {
                const bool doG = (it >= 2);             // gates for step it-2
                const bool doQ = (it >= 1 && it <= TT); // pI(it-1) for next iter

                // ds_reads first (both frag sets issue together)
                half8 a2, a3, b0, b1;
                if (doG) {
                    const _Float16* hb2 = h2a[prev] + (l16 & 3) * HSTR + quad * 8;
                    a2 = *(const half8*)hb2;
                    a3 = *(const half8*)(hb2 + 32);
                }
                if (doQ) {
                    const _Float16* hb1 = h1a[prev] + (l16 & 3) * HSTR + quad * 8;
                    b0 = *(const half8*)hb1;
                    b1 = *(const half8*)(hb1 + 32);
                }

                // read-window fill: pI(it-2) quad-selects (off the tail chain)
                float qp0, qp1, qp2, qp3;
                if (doG) {
                    qp0 = sel4(accQ[prev][0], quad);
                    qp1 = sel4(accQ[prev][1], quad);
                    qp2 = sel4(accQ[prev][2], quad);
                    qp3 = sel4(accQ[prev][3], quad);
                }

                // CRITICAL: gate MFMAs issue first (in-order MFMA pipe).
                f32x4 acc[4];
                if (doG) {
                    #pragma unroll
                    for (int c = 0; c < 4; ++c) {
                        f32x4 z = cbias[c];
                        z = __builtin_amdgcn_mfma_f32_16x16x32_f16(a2, wA[c][0], z, 0, 0, 0);
                        z = __builtin_amdgcn_mfma_f32_16x16x32_f16(a3, wA[c][1], z, 0, 0, 0);
                        acc[c] = z;
                    }
                }
                // pI(it-1) = Wih1 . h1[it-1] -> accQ[sub] (registers, consumed
                // NEXT iteration). Off-critical; issues behind gates, completes
                // under the VALU activation tail.
                if (doQ) {
                    #pragma unroll
                    for (int c = 0; c < 4; ++c) {
                        f32x4 z = Z;
                        z = __builtin_amdgcn_mfma_f32_16x16x32_f16(b0, wB[c][0], z, 0, 0, 0);
                        z = __builtin_amdgcn_mfma_f32_16x16x32_f16(b1, wB[c][1], z, 0, 0, 0);
                        accQ[sub][c] = z;
                    }
                }

                if (doG) {
                    // gates = Whh1.h2[it-3] + bias + pI(it-2) (hoisted qp)
                    float pi = sel4(acc[0], quad) + qp0;
                    float pf = sel4(acc[1], quad) + qp1;
                    float pg = sel4(acc[2], quad) + qp2;
                    float po = sel4(acc[3], quad) + qp3;
                    float iv = sig_p(pi),  fv = sig_p(pf);
                    float gv = tanh_p(pg), ov = sig_p(po);
                    cst = fmaf(fv, cst, iv * gv);
                    float hv = ov * tanh_p(cst * LOG2E2);
                    h2a[cur][quad * HSTR + col] = (_Float16)hv;            // h2[it-2]
                    if (it == TT + 1)
                        out[(size_t)(blockIdx.x * 4 + quad) * 64 + col] = hv;
                }
            }
            lds_barrier();   // LDS-only drain; x prefetch stays in flight
        }
    }
}

extern "C" void kernel_launch(void* const* d_in, const int* in_sizes, int n_in,
                              void* d_out, int out_size, void* d_ws, size_t ws_size,
                              hipStream_t stream) {
    const float* x    = (const float*)d_in[0];
    const float* Wih0 = (const float*)d_in[1];
    const float* Whh0 = (const float*)d_in[2];
    const float* bih0 = (const float*)d_in[3];
    const float* bhh0 = (const float*)d_in[4];
    const float* Wih1 = (const float*)d_in[5];
    const float* Whh1 = (const float*)d_in[6];
    const float* bih1 = (const float*)d_in[7];
    const float* bhh1 = (const float*)d_in[8];
    float* out = (float*)d_out;

    // 512 sequences / 4 per block = 128 blocks; 512 threads (8 waves, 2/SIMD).
    lstm2_fused<<<128, 512, 0, stream>>>(x, Wih0, Whh0, bih0, bhh0,
                                         Wih1, Whh1, bih1, bhh1, out);
}

// Round 13
// 931.238 us; speedup vs baseline: 1.0585x; 1.0099x over previous
//
#include <hip/hip_runtime.h>
#include <math.h>

// BiometricLSTM: 2-layer LSTM, B=512, T=2048, I=3, H=64, fp32 in/out. Output = final h2 (B,64).
//
// R30: R29 (best, 940.5 us; setprio kept — measured neutral) + two chain cuts
// on the activation tail. The surviving model: T_iter ~550cy @ ~1.2GHz is the
// serial chain (barrier -> ds_read ~130 -> MFMA z-pair ~40 -> sel4 -> act tail
// ~60 -> cvt/write/drain ~40); VALU+MFMA busy 47%, rest is dependency stall.
// Three scheduling theories refuted (vmcnt drain R24, x latency R27, prio R29).
//  (1) f-gate-first MFMA order {f,i,g,o}: c = fv*cst + iv*gv consumes fv first,
//      ov last. Staggers the 4 parallel activation chains so the c-fma inputs
//      arrive earliest. Pure issue reorder; per-class arithmetic identical.
//  (2) fused tanh multiplies: after r = rcp(exp2(y)+1), old chain was
//      fma(-2,r,1) -> mul (2 deps). New: precompute m2iv=-2*iv / m2ov=-2*ov
//      OFF-chain (iv/ov ready in parallel), then igv = fmaf(m2iv, r_g, iv) and
//      hv = fmaf(m2ov, r_h, ov) (1 dep each). Cuts 2 serial ops per step per
//      role. One fewer rounding -> absmax may move a ulp from 4.88e-4.
// R26-R29 recap (all kept): log2e-prescaled weights/biases (bare v_exp2),
// L1 read-window sel4 hoists, 2-level sel4 tree; split waves L0=Whh0 8 MFMA /
// L1=Whh1+Wih1 16 MFMA lag-2; pI in registers accQ[2][4] (write@sub,
// read@sub^1), no pIbuf, LDS 2560B, 0 bank conflicts; gates-before-pI issue
// order; unroll-2 compile-time parity; M=4 replicated rows; quad-selected
// update; HSTR=80; z-chained MFMA pairs bias-in-C; x prefetch depth-1;
// lds_barrier (lgkmcnt-only drain) once per iter; setprio(1) on L0;
// f16 weights/h + f32 accum.
// Parities: h1[t]@t&1; h2[t]@t&1; accQ write@sub / read@sub^1.

typedef _Float16 half8 __attribute__((ext_vector_type(8)));
typedef float    f32x4 __attribute__((ext_vector_type(4)));

constexpr int TT = 2048;
constexpr int HSTR = 80;   // h row stride in halves (160 B)

#define LOG2E  1.44269504088896340736f
#define LOG2E2 2.88539008177792681472f

// y = x*log2e applied upstream: sigmoid(x) = 1/(1+2^-y)
__device__ __forceinline__ float sig_p(float y) {
    return __builtin_amdgcn_rcpf(1.0f + __builtin_amdgcn_exp2f(-y));
}
// y = x*2log2e applied upstream: r = 1/(2^y+1); tanh(x) = 1 - 2r
__device__ __forceinline__ float tanh_r(float y) {
    return __builtin_amdgcn_rcpf(__builtin_amdgcn_exp2f(y) + 1.0f);
}
// select component q (lane's quad) from an f32x4 accumulator — 2-level tree
__device__ __forceinline__ float sel4(f32x4 v, int q) {
    float lo = (q & 1) ? v[1] : v[0];
    float hi = (q & 1) ? v[3] : v[2];
    return (q & 2) ? hi : lo;
}

// Barrier with LDS-only drain: s_waitcnt lgkmcnt(0) + s_barrier.
// Does NOT drain vmcnt — in-flight global x-prefetch loads stay in flight.
__device__ __forceinline__ void lds_barrier() {
    __builtin_amdgcn_sched_barrier(0);
    asm volatile("s_waitcnt lgkmcnt(0)" ::: "memory");
    __builtin_amdgcn_s_barrier();
    __builtin_amdgcn_sched_barrier(0);
}

__global__ __launch_bounds__(512) void lstm2_fused(
    const float* __restrict__ x,
    const float* __restrict__ Wih0, const float* __restrict__ Whh0,
    const float* __restrict__ bih0, const float* __restrict__ bhh0,
    const float* __restrict__ Wih1, const float* __restrict__ Whh1,
    const float* __restrict__ bih1, const float* __restrict__ bhh1,
    float* __restrict__ out)
{
    __shared__ __align__(16) _Float16 h1a[2][4 * HSTR];   // [parity][seq*HSTR + elem]
    __shared__ __align__(16) _Float16 h2a[2][4 * HSTR];

    const int tid  = threadIdx.x;
    const int lane = tid & 63;
    const int wid  = tid >> 6;
    const int quad = lane >> 4;
    const int l16  = lane & 15;
    const bool isL1 = (wid >= 4);
    const int col  = (wid & 3) * 16 + l16;   // gate-elem column this lane owns per class

    // ---- zero h double-buffers ----
    for (int i = tid; i < 2 * 4 * HSTR; i += 512) {
        ((_Float16*)h1a)[i] = (_Float16)0.0f;
        ((_Float16*)h2a)[i] = (_Float16)0.0f;
    }

    // ---- weights (B-frags, f16), log2e-prescaled per gate class ----
    // class c: 0=i 1=f 2=g 3=o; scale = log2e (sigmoid) or 2*log2e (tanh g)
    half8 wA[4][2];      // L0 waves: Whh0 | L1 waves: Whh1
    half8 wB[4][2];      // L1 waves only: Wih1
    f32x4 cbias[4];      // bias splat (prescaled), MFMA C-init
    float wxa[4], wxb[4], wxc[4];            // L0 only (prescaled)
    #pragma unroll
    for (int c = 0; c < 4; ++c) {
        const int row = c * 64 + col;
        const float sc = (c == 2) ? LOG2E2 : LOG2E;
        if (!isL1) {
            #pragma unroll
            for (int f = 0; f < 2; ++f) {
                const float* p = Whh0 + (size_t)row * 64 + f * 32 + quad * 8;
                half8 h;
                #pragma unroll
                for (int u = 0; u < 8; ++u) h[u] = (_Float16)(p[u] * sc);
                wA[c][f] = h;
            }
            const float b = (bih0[row] + bhh0[row]) * sc;
            cbias[c] = f32x4{b, b, b, b};
            wxa[c] = Wih0[row*3+0] * sc;
            wxb[c] = Wih0[row*3+1] * sc;
            wxc[c] = Wih0[row*3+2] * sc;
        } else {
            #pragma unroll
            for (int f = 0; f < 2; ++f) {
                const float* p = Whh1 + (size_t)row * 64 + f * 32 + quad * 8;
                half8 h;
                #pragma unroll
                for (int u = 0; u < 8; ++u) h[u] = (_Float16)(p[u] * sc);
                wA[c][f] = h;
                const float* q = Wih1 + (size_t)row * 64 + f * 32 + quad * 8;
                half8 g;
                #pragma unroll
                for (int u = 0; u < 8; ++u) g[u] = (_Float16)(q[u] * sc);
                wB[c][f] = g;
            }
            const float b = (bih1[row] + bhh1[row]) * sc;
            cbias[c] = f32x4{b, b, b, b};
        }
    }

    // ---- x prefetch (L0 waves), depth 1: this lane's seq = quad ----
    const float* xq = x + (size_t)(blockIdx.x * 4 + quad) * TT * 3;
    float xn0 = 0.f, xn1 = 0.f, xn2 = 0.f;
    if (!isL1) { xn0 = xq[0]; xn1 = xq[1]; xn2 = xq[2]; }

    const f32x4 Z = {0.f, 0.f, 0.f, 0.f};
    float cst = 0.0f;    // cell state (layer per role, seq=quad, elem=col)

    // L1: pI double-buffer in registers; accQ[sub] written at parity sub,
    // read at sub^1. Indices are compile-time after the unroll (rule #20).
    f32x4 accQ[2][4];
    #pragma unroll
    for (int s = 0; s < 2; ++s)
        #pragma unroll
        for (int c = 0; c < 4; ++c) accQ[s][c] = Z;

    // protect the h1-recurrence wave at issue-contention points (R29: neutral,
    // kept — no cost).
    if (!isL1) __builtin_amdgcn_s_setprio(1);

    __syncthreads();   // init barrier: full drain fine here (once)

    // MFMA issue order: f first (c-update consumes fv first), o last.
    const int ORD[4] = {1, 0, 2, 3};

    // iter it = 0 .. TT+1 in unrolled pairs (cur/prev compile-time).
    // L0: step it (it<TT).  L1: gates for step it-2 (it>=2) + pI(it-1) (1<=it<=TT).
    // ONE lds_barrier per iteration.
    for (int bt = 0; bt <= TT + 1; bt += 2) {
        #pragma unroll
        for (int sub = 0; sub < 2; ++sub) {
            const int it   = bt + sub;
            const int cur  = sub;        // bt even => it&1 == sub
            const int prev = sub ^ 1;

            if (!isL1) {
                if (it < TT) {
                    // A-frags: h1[it-1] (parity prev), replicated rows
                    const _Float16* hb = h1a[prev] + (l16 & 3) * HSTR + quad * 8;
                    half8 a0 = *(const half8*)hb;
                    half8 a1 = *(const half8*)(hb + 32);

                    // x-projection (prescaled): fills the ds_read window.
                    const float x0 = xn0, x1 = xn1, x2 = xn2;
                    float xp0 = fmaf(wxa[0], x0, fmaf(wxb[0], x1, wxc[0] * x2));
                    float xp1 = fmaf(wxa[1], x0, fmaf(wxb[1], x1, wxc[1] * x2));
                    float xp2 = fmaf(wxa[2], x0, fmaf(wxb[2], x1, wxc[2] * x2));
                    float xp3 = fmaf(wxa[3], x0, fmaf(wxb[3], x1, wxc[3] * x2));
                    const int nt = (it + 1 < TT) ? it + 1 : TT - 1;
                    const float* np = xq + nt * 3;
                    xn0 = np[0]; xn1 = np[1]; xn2 = np[2];

                    // L0 gates: Whh0 . h1[it-1] + bias (in C), f-class first.
                    f32x4 acc[4];
                    #pragma unroll
                    for (int k = 0; k < 4; ++k) {
                        const int c = ORD[k];
                        f32x4 z = cbias[c];
                        z = __builtin_amdgcn_mfma_f32_16x16x32_f16(a0, wA[c][0], z, 0, 0, 0);
                        z = __builtin_amdgcn_mfma_f32_16x16x32_f16(a1, wA[c][1], z, 0, 0, 0);
                        acc[c] = z;
                    }
                    float pf = sel4(acc[1], quad) + xp1;
                    float pi = sel4(acc[0], quad) + xp0;
                    float pg = sel4(acc[2], quad) + xp2;
                    float po = sel4(acc[3], quad) + xp3;
                    float fv = sig_p(pf), iv = sig_p(pi), ov = sig_p(po);
                    float rg = tanh_r(pg);
                    float m2iv = -2.0f * iv;                 // off-chain
                    float igv = fmaf(m2iv, rg, iv);          // iv*tanh(g), 1 dep
                    cst = fmaf(fv, cst, igv);
                    float m2ov = -2.0f * ov;                 // off-chain (c runs)
                    float rh = tanh_r(cst * LOG2E2);
                    float hv = fmaf(m2ov, rh, ov);           // ov*tanh(c), 1 dep
                    h1a[cur][quad * HSTR + col] = (_Float16)hv;   // h1[it]
                }
            } else {
                const bool doG = (it >= 2);             // gates for step it-2
                const bool doQ = (it >= 1 && it <= TT); // pI(it-1) for next iter

                // ds_reads first (both frag sets issue together)
                half8 a2, a3, b0, b1;
                if (doG) {
                    const _Float16* hb2 = h2a[prev] + (l16 & 3) * HSTR + quad * 8;
                    a2 = *(const half8*)hb2;
                    a3 = *(const half8*)(hb2 + 32);
                }
                if (doQ) {
                    const _Float16* hb1 = h1a[prev] + (l16 & 3) * HSTR + quad * 8;
                    b0 = *(const half8*)hb1;
                    b1 = *(const half8*)(hb1 + 32);
                }

                // read-window fill: pI(it-2) quad-selects (off the tail chain)
                float qp0, qp1, qp2, qp3;
                if (doG) {
                    qp0 = sel4(accQ[prev][0], quad);
                    qp1 = sel4(accQ[prev][1], quad);
                    qp2 = sel4(accQ[prev][2], quad);
                    qp3 = sel4(accQ[prev][3], quad);
                }

                // CRITICAL: gate MFMAs issue first, f-class first.
                f32x4 acc[4];
                if (doG) {
                    #pragma unroll
                    for (int k = 0; k < 4; ++k) {
                        const int c = ORD[k];
                        f32x4 z = cbias[c];
                        z = __builtin_amdgcn_mfma_f32_16x16x32_f16(a2, wA[c][0], z, 0, 0, 0);
                        z = __builtin_amdgcn_mfma_f32_16x16x32_f16(a3, wA[c][1], z, 0, 0, 0);
                        acc[c] = z;
                    }
                }
                // pI(it-1) = Wih1 . h1[it-1] -> accQ[sub] (registers, consumed
                // NEXT iteration). Off-critical; issues behind gates.
                if (doQ) {
                    #pragma unroll
                    for (int c = 0; c < 4; ++c) {
                        f32x4 z = Z;
                        z = __builtin_amdgcn_mfma_f32_16x16x32_f16(b0, wB[c][0], z, 0, 0, 0);
                        z = __builtin_amdgcn_mfma_f32_16x16x32_f16(b1, wB[c][1], z, 0, 0, 0);
                        accQ[sub][c] = z;
                    }
                }

                if (doG) {
                    // gates = Whh1.h2[it-3] + bias + pI(it-2) (hoisted qp)
                    float pf = sel4(acc[1], quad) + qp1;
                    float pi = sel4(acc[0], quad) + qp0;
                    float pg = sel4(acc[2], quad) + qp2;
                    float po = sel4(acc[3], quad) + qp3;
                    float fv = sig_p(pf), iv = sig_p(pi), ov = sig_p(po);
                    float rg = tanh_r(pg);
                    float m2iv = -2.0f * iv;
                    float igv = fmaf(m2iv, rg, iv);
                    cst = fmaf(fv, cst, igv);
                    float m2ov = -2.0f * ov;
                    float rh = tanh_r(cst * LOG2E2);
                    float hv = fmaf(m2ov, rh, ov);
                    h2a[cur][quad * HSTR + col] = (_Float16)hv;   // h2[it-2]
                    if (it == TT + 1)
                        out[(size_t)(blockIdx.x * 4 + quad) * 64 + col] = hv;
                }
            }
            lds_barrier();   // LDS-only drain; x prefetch stays in flight
        }
    }
}

extern "C" void kernel_launch(void* const* d_in, const int* in_sizes, int n_in,
                              void* d_out, int out_size, void* d_ws, size_t ws_size,
                              hipStream_t stream) {
    const float* x    = (const float*)d_in[0];
    const float* Wih0 = (const float*)d_in[1];
    const float* Whh0 = (const float*)d_in[2];
    const float* bih0 = (const float*)d_in[3];
    const float* bhh0 = (const float*)d_in[4];
    const float* Wih1 = (const float*)d_in[5];
    const float* Whh1 = (const float*)d_in[6];
    const float* bih1 = (const float*)d_in[7];
    const float* bhh1 = (const float*)d_in[8];
    float* out = (float*)d_out;

    // 512 sequences / 4 per block = 128 blocks; 512 threads (8 waves, 2/SIMD).
    lstm2_fused<<<128, 512, 0, stream>>>(x, Wih0, Whh0, bih0, bhh0,
                                         Wih1, Whh1, bih1, bhh1, out);
}